// Round 10
// baseline (2969.398 us; speedup 1.0000x reference)
//
#include <hip/hip_runtime.h>

#define TPB 256
#define NWG 32
#define B_  8
#define H_  512
#define E_  256
#define SE_ 128
#define SD_ 256
#define WS  530   // f16 weight row stride (u16 units), even -> 4B aligned pairs

typedef unsigned short u16;
typedef unsigned int   u32;
typedef __attribute__((ext_vector_type(4))) float f32x4;
typedef __attribute__((ext_vector_type(8))) short short8;
typedef __attribute__((ext_vector_type(2))) _Float16 half2v;

#define SENTU 0x7FC00001u

// ---------------- numeric helpers ----------------
__device__ __forceinline__ u16 f2b(float f){
  u32 u = __float_as_uint(f);
  u = (u + 0x7fffu + ((u >> 16) & 1u)) >> 16;   // RNE f32->bf16
  return (u16)u;
}
__device__ __forceinline__ u16 f2h(float f){
  _Float16 h = (_Float16)f;
  return __builtin_bit_cast(unsigned short, h);
}
__device__ __forceinline__ void b2f2(u32 p, float& a, float& b){
  a = __uint_as_float(p << 16);
  b = __uint_as_float(p & 0xffff0000u);
}
__device__ __forceinline__ float ftanh(float x){
  float e = __expf(2.f * x);
  return 1.f - 2.f / (e + 1.f);
}
__device__ __forceinline__ float red16(float v){
  v += __shfl_xor(v, 1); v += __shfl_xor(v, 2);
  v += __shfl_xor(v, 4); v += __shfl_xor(v, 8);
  return v;
}
__device__ __forceinline__ float sentf(){ return __uint_as_float(SENTU); }
__device__ __forceinline__ bool issent(float x){ return __float_as_uint(x) == SENTU; }
__device__ __forceinline__ float dot2h(half2v w, half2v x, float acc){
#if __has_builtin(__builtin_amdgcn_fdot2)
  return __builtin_amdgcn_fdot2(w, x, acc, false);
#else
  return acc + (float)w.x * (float)x.x + (float)w.y * (float)x.y;
#endif
}
__device__ __forceinline__ float ldsflag(float* f){ return *(volatile float*)f; }
__device__ __forceinline__ void stsflag(float* f, float v){ *(volatile float*)f = v; }

// Coherent primitives (proven R3/R7): relaxed agent-scope atomics = sc0 sc1 ops.
__device__ __forceinline__ float gld(const float* p){
  return __hip_atomic_load(p, __ATOMIC_RELAXED, __HIP_MEMORY_SCOPE_AGENT);
}
__device__ __forceinline__ void gst(float* p, float v){
  __hip_atomic_store(p, v, __ATOMIC_RELAXED, __HIP_MEMORY_SCOPE_AGENT);
}

// packed-publication indexing (R7)
__device__ __forceinline__ int HPX(int slot,int b,int wg,int r){ return ((slot*8+b)*32+wg)*16+r; }
__device__ __forceinline__ int HPB(int slot,int b){ return (slot*8+b)*512; }
__device__ __forceinline__ int PPX(int slot,int b,int wg,int s){ return ((slot*8+b)*32+wg)*128+s; }
__device__ __forceinline__ int PPB(int slot,int b){ return (slot*8+b)*4096; }

// Staggered full-range poll-gather: each of the 4 waves independently polls
// the whole 512-float block (phase-offset ~RT/4 via s_sleep). First wave to
// see all values final stages ALL of them to LDS (idempotent), lgkm-fences,
// sets flag; other waves early-exit on the flag. No dangling loads.
// Caller: __syncthreads() to join, then tid==0 resets flag (>=1 sync before
// the flag's next use exists in all call paths).
__device__ __forceinline__ void pollgather_dual(const float* base, half2v* dsth, float* flg){
  const int tid = threadIdx.x;
  const int wv = tid >> 6, l = tid & 63;
  if (wv == 1)      __builtin_amdgcn_s_sleep(6);
  else if (wv == 2) __builtin_amdgcn_s_sleep(12);
  else if (wv == 3) __builtin_amdgcn_s_sleep(18);
  const float* p = base + l*8;
  f32x4 v0, v1;
  for (;;){
    if (ldsflag(flg) != 0.f) return;   // another wave already staged the block
    asm volatile("global_load_dwordx4 %0, %2, off sc0 sc1\n\t"
                 "global_load_dwordx4 %1, %2, off offset:16 sc0 sc1\n\t"
                 "s_waitcnt vmcnt(0)"
                 : "=v"(v0), "=v"(v1) : "v"(p) : "memory");
    bool ok = !issent(v0.x) & !issent(v0.y) & !issent(v0.z) & !issent(v0.w)
            & !issent(v1.x) & !issent(v1.y) & !issent(v1.z) & !issent(v1.w);
    if (__all(ok)) break;
    __builtin_amdgcn_s_sleep(1);
  }
  half2v h0, h1, h2, h3;
  h0.x = (_Float16)v0.x; h0.y = (_Float16)v0.y;
  h1.x = (_Float16)v0.z; h1.y = (_Float16)v0.w;
  h2.x = (_Float16)v1.x; h2.y = (_Float16)v1.y;
  h3.x = (_Float16)v1.z; h3.y = (_Float16)v1.w;
  dsth[l*4]     = h0; dsth[l*4 + 1] = h1;
  dsth[l*4 + 2] = h2; dsth[l*4 + 3] = h3;
  asm volatile("s_waitcnt lgkmcnt(0)" ::: "memory");  // data before flag
  if (l == 0) stsflag(flg, 1.f);
}

// ---------------- params ----------------
struct Inputs {
  const int   *enc_input, *target;
  const float *enc_emb;
  const float *enc_Wi1, *enc_bi1, *enc_Wh1, *enc_bh1;
  const float *enc_Wi2, *enc_bi2, *enc_Wh2, *enc_bh2;
  const float *dec_emb;
  const float *attn_We, *attn_be, *attn_Wh, *attn_bh, *attn_V, *attn_bV;
  const float *dec_Wi1, *dec_bi1, *dec_Wh1, *dec_bh1;
  const float *dec_Wi2, *dec_bi2, *dec_Wh2, *dec_bh2;
  const float *out_W, *out_b;
};
struct Wksp {
  u32*  bar;
  float *hbuf, *h1buf, *h2buf, *partials;  // packed 4-slot sentinel buffers (R7)
  float *xi1, *xi2, *out1, *encout, *xe;   // live in d_out (consumed pre-GEMM)
  u16   *h2all, *wb;
};

// ---------------- LDS layout (bytes) ----------------
constexpr int OFF_A   = 0;        // dec: Wh1s f16[16][530] | enc: WaE
constexpr int OFF_A2  = 17024;    // dec: Ws2s f16[16][530] | enc: WbE (scan, f16)
constexpr int OFF_A3  = 34048;    // dec: Wats f16[16][530] | enc: 16KB staging
constexpr int OFF_PM  = 51008;    // f32 [16][128]  P matrix
constexpr int OFF_PES = 59200;    // f32 [128][17]  pe slice (padded)
constexpr int OFF_STG = 67904;    // f32 [2048]     setup staging
constexpr int OFF_WRG = 76096;    // f32 [16][768]  Wi1 own rows (setup)
constexpr int OFF_XVH = 125248;   // half[512]  (P2 h1 vector / enc h vector)
constexpr int OFF_XV2H= 126272;   // half[512]  (P13 h2 vector)
constexpr int OFF_ES  = 127296;   // f32 [128]
constexpr int OFF_QS  = 127808;   // f32 [16]
constexpr int OFF_VS  = 127872;   // f32 [16]
constexpr int OFF_B1  = 127936;
constexpr int OFF_B2  = 128000;
constexpr int OFF_BH  = 128064;
constexpr int OFF_BSC = 128128;
constexpr int OFF_SCR = 128192;   // f32 [16]: [0] den, [8] bV, [12] fH, [13] fP
constexpr int LDS_BYTES = 128256;

// ---------------- stage barrier (proven R3) ----------------
__device__ __forceinline__ void cbar(u32* slots, int wg, u32 target){
  asm volatile("s_waitcnt vmcnt(0)" ::: "memory");
  __syncthreads();
  const int tid = threadIdx.x;
  if (tid < 64){
    if (tid == 0)
      __hip_atomic_store(&slots[wg], target, __ATOMIC_RELAXED, __HIP_MEMORY_SCOPE_AGENT);
    bool done = false;
    do {
      u32 v = __hip_atomic_load(&slots[tid & 31], __ATOMIC_RELAXED, __HIP_MEMORY_SCOPE_AGENT);
      done = (v >= target);
    } while (__ballot(done) != ~0ull);
  }
  __syncthreads();
  asm volatile("" ::: "memory");
}

// ---------------- encoder scan: R7 sentinel dataflow, staggered polls ----------------
__device__ void enc_scan(const Wksp& w,
                         const float* __restrict__ Wh, const float* __restrict__ bh,
                         const float* __restrict__ xi, float* __restrict__ outbuf,
                         int b, int wg, u16* WbE, half2v* xvh, float* bscan, float* flg)
{
  const int tid = threadIdx.x;
  for (int i = tid; i < 16*512; i += TPB){
    int r = i >> 9, j = i & 511;
    WbE[r*WS + j] = f2h(Wh[((size_t)(wg*16 + r))*H_ + j]);
  }
  if (tid < 16) bscan[tid] = bh[wg*16 + tid];
  __syncthreads();
  for (int t = 0; t < SE_; t++){
    pollgather_dual(&w.hbuf[HPB(t&3, b)], xvh, flg);
    __syncthreads();                         // join
    if (tid == 0) stsflag(flg, 0.f);         // reset (end-of-step sync orders it)
    int r = tid >> 4, sl = tid & 15;
    float acc = 0.f;
    #pragma unroll
    for (int k = 0; k < 16; k++){
      int jj = sl + 16*k;
      acc = dot2h(*(const half2v*)&WbE[r*WS + 2*jj], xvh[jj], acc);
    }
    acc = red16(acc);
    if (sl == 0){
      int row = wg*16 + r;
      float hv = ftanh(xi[((size_t)b*SE_ + t)*H_ + row] + acc + bscan[r]);
      gst(&w.hbuf[HPX((t+1)&3, b, wg, r)], hv);          // publish
      gst(&outbuf[((size_t)b*SE_ + t)*H_ + row], hv);    // bulk history
      gst(&w.hbuf[HPX((t+3)&3, b, wg, r)], sentf());     // poison
    }
    asm volatile("s_waitcnt vmcnt(0)" ::: "memory");
    __syncthreads();
  }
}

// ---------------- persistent seq2seq kernel ----------------
__global__ __launch_bounds__(TPB, 1) void seq2seq_persist(Inputs in, Wksp w)
{
  __shared__ __attribute__((aligned(16))) unsigned char S[LDS_BYTES];
  u16* Wh1s = (u16*)(S + OFF_A);
  u16* Ws2s = (u16*)(S + OFF_A2);
  u16* Wats = (u16*)(S + OFF_A3);
  u16* WaE  = (u16*)(S + OFF_A);    // encoder aliases
  u16* WbE  = (u16*)(S + OFF_A2);
  float* stgE = (float*)(S + OFF_A3);
  float* Pm   = (float*)(S + OFF_PM);
  float* pes  = (float*)(S + OFF_PES);
  float* STG  = (float*)(S + OFF_STG);
  float* WRG  = (float*)(S + OFF_WRG);
  half2v* xvh  = (half2v*)(S + OFF_XVH);
  half2v* xv2h = (half2v*)(S + OFF_XV2H);
  float* es   = (float*)(S + OFF_ES);
  float* qs   = (float*)(S + OFF_QS);
  float* Vs   = (float*)(S + OFF_VS);
  float* b1s  = (float*)(S + OFF_B1);
  float* b2s  = (float*)(S + OFF_B2);
  float* bhs  = (float*)(S + OFF_BH);
  float* bscan= (float*)(S + OFF_BSC);
  float* scr  = (float*)(S + OFF_SCR);
  float* fH   = scr + 12;
  float* fP   = scr + 13;

  const int bid = blockIdx.x;
  const int c = bid & 7, wg = bid >> 3;   // cluster = batch, 32 WGs
  const int b = c;
  const int tid = threadIdx.x;
  u32* slots = w.bar + c*32;
  u32 bt = 0;

  // ---- initial state: flags zero; h0 real (packed); other slots poisoned ----
  if (tid == 0){ stsflag(fH, 0.f); stsflag(fP, 0.f); }
  if (tid < 16){
    gst(&w.hbuf[HPX(0, b, wg, tid)], 0.f);
    #pragma unroll
    for (int s2 = 1; s2 < 4; s2++) gst(&w.hbuf[HPX(s2, b, wg, tid)], sentf());
    #pragma unroll
    for (int s2 = 0; s2 < 4; s2++) gst(&w.h1buf[HPX(s2, b, wg, tid)], sentf());
    #pragma unroll
    for (int s2 = 0; s2 < 3; s2++) gst(&w.h2buf[HPX(s2, b, wg, tid)], sentf());
  }
  if (tid < 128){
    #pragma unroll
    for (int s2 = 0; s2 < 3; s2++) gst(&w.partials[PPX(s2, b, wg, tid)], sentf());
  }

  // ---- encoder layer1 input GEMM (xi1 = emb @ Wi1^T + bi1), WG-private ----
  for (int i = tid; i < 16*256; i += TPB){
    int r = i >> 8, j = i & 255;
    WaE[r*264 + j] = f2b(in.enc_Wi1[((size_t)(wg*16 + r))*E_ + j]);
  }
  if (tid < 16) bscan[tid] = in.enc_bi1[wg*16 + tid];
  __syncthreads();
  for (int k0 = 0; k0 < 8; k0++){
    for (int it = 0; it < 16; it++){
      int tok = in.enc_input[b*SE_ + k0*16 + it];
      stgE[it*256 + tid] = in.enc_emb[(size_t)tok*E_ + tid];
    }
    __syncthreads();
    int r = tid & 15, tt = tid >> 4;
    float acc = 0.f;
    #pragma unroll 16
    for (int j = 0; j < 256; j += 2){
      u32 p = *(const u32*)&WaE[r*264 + j];
      float w0, w1; b2f2(p, w0, w1);
      float2 x = *(const float2*)&stgE[tt*256 + j];
      acc += w0*x.x + w1*x.y;
    }
    w.xi1[((size_t)b*SE_ + k0*16 + tt)*H_ + wg*16 + r] = acc + bscan[r];
    __syncthreads();
  }
  cbar(slots, wg, ++bt);

  // ---- encoder layer1 scan ----
  enc_scan(w, in.enc_Wh1, in.enc_bh1, w.xi1, w.out1, b, wg, WbE, xvh, bscan, fH);
  cbar(slots, wg, ++bt);

  // ---- xi2 = out1 @ Wi2^T + bi2 ; re-poison hbuf slots 1..3 for L2 scan ----
  for (int i = tid; i < 16*512; i += TPB){
    int r = i >> 9, j = i & 511;
    WaE[r*522 + j] = f2b(in.enc_Wi2[((size_t)(wg*16 + r))*H_ + j]);
  }
  if (tid < 16){
    bscan[tid] = in.enc_bi2[wg*16 + tid];
    #pragma unroll
    for (int s2 = 1; s2 < 4; s2++) gst(&w.hbuf[HPX(s2, b, wg, tid)], sentf());
  }
  __syncthreads();
  {
    u16* stg2 = (u16*)stgE;
    for (int k0 = 0; k0 < 8; k0++){
      for (int it = 0; it < 16; it++){
        size_t base = ((size_t)b*SE_ + k0*16 + it)*H_;
        stg2[it*512 + tid]       = f2b(gld(&w.out1[base + tid]));
        stg2[it*512 + tid + 256] = f2b(gld(&w.out1[base + tid + 256]));
      }
      __syncthreads();
      int r = tid & 15, tt = tid >> 4;
      float acc = 0.f;
      #pragma unroll 16
      for (int j = 0; j < 512; j += 2){
        u32 p  = *(const u32*)&WaE[r*522 + j];
        u32 s2 = *(const u32*)&stg2[tt*512 + j];
        float w0, w1, s0, s1; b2f2(p, w0, w1); b2f2(s2, s0, s1);
        acc += w0*s0 + w1*s1;
      }
      w.xi2[((size_t)b*SE_ + k0*16 + tt)*H_ + wg*16 + r] = acc + bscan[r];
      __syncthreads();
    }
  }
  cbar(slots, wg, ++bt);

  // ---- encoder layer2 scan (initial hidden = L1 final, already in slot 0) ----
  enc_scan(w, in.enc_Wh2, in.enc_bh2, w.xi2, w.encout, b, wg, WbE, xvh, bscan, fH);
  cbar(slots, wg, ++bt);

  // ======== decoder setup ========
  for (int i = tid; i < 16*768; i += TPB)
    WRG[i] = in.dec_Wi1[(size_t)(wg*16 + i/768)*768 + (i - (i/768)*768)];
  for (int tb = 0; tb < 32; tb++){
    __syncthreads();
    for (int i = tid; i < 8*256; i += TPB){
      int tt = tb*8 + (i >> 8);
      int tok = in.target[b*SD_ + (tt == 0 ? 0 : tt - 1)];
      STG[i] = in.dec_emb[(size_t)tok*E_ + (i & 255)];
    }
    __syncthreads();
    int r = tid >> 4, sl = tid & 15;
    for (int t2 = 0; t2 < 8; t2++){
      float acc = 0.f;
      #pragma unroll
      for (int k = 0; k < 8; k++){
        int j = 2*sl + 32*k;
        float2 wv = *(const float2*)&WRG[r*768 + j];
        float2 xx = *(const float2*)&STG[t2*256 + j];
        acc += wv.x*xx.x + wv.y*xx.y;
      }
      acc = red16(acc);
      if (sl == 0) w.xe[((size_t)b*SD_ + tb*8 + t2)*H_ + wg*16 + r] = acc;
    }
  }
  for (int sb = 0; sb < 32; sb++){
    __syncthreads();
    for (int i = tid; i < 4*512; i += TPB)
      STG[i] = gld(&w.encout[((size_t)b*SE_ + sb*4 + (i >> 9))*H_ + (i & 511)]);
    __syncthreads();
    int r = tid >> 4, sl = tid & 15;
    const float* wer = in.attn_We + (size_t)(wg*16 + r)*H_;
    float a0=0.f, a1=0.f, a2=0.f, a3=0.f;
    float p0=0.f, p1=0.f, p2=0.f, p3=0.f;
    #pragma unroll
    for (int k = 0; k < 16; k++){
      int j = 2*sl + 32*k;
      float2 wv = *(const float2*)&wer[j];
      float2 x0 = *(const float2*)&STG[j];
      float2 x1 = *(const float2*)&STG[512 + j];
      float2 x2 = *(const float2*)&STG[1024 + j];
      float2 x3 = *(const float2*)&STG[1536 + j];
      a0 += wv.x*x0.x + wv.y*x0.y;  a1 += wv.x*x1.x + wv.y*x1.y;
      a2 += wv.x*x2.x + wv.y*x2.y;  a3 += wv.x*x3.x + wv.y*x3.y;
      float2 cv = *(const float2*)&WRG[r*768 + 256 + j];
      p0 += cv.x*x0.x + cv.y*x0.y;  p1 += cv.x*x1.x + cv.y*x1.y;
      p2 += cv.x*x2.x + cv.y*x2.y;  p3 += cv.x*x3.x + cv.y*x3.y;
    }
    a0 = red16(a0); a1 = red16(a1); a2 = red16(a2); a3 = red16(a3);
    p0 = red16(p0); p1 = red16(p1); p2 = red16(p2); p3 = red16(p3);
    if (sl == 0){
      float bed = in.attn_be[wg*16 + r];
      pes[(sb*4 + 0)*17 + r] = a0 + bed;
      pes[(sb*4 + 1)*17 + r] = a1 + bed;
      pes[(sb*4 + 2)*17 + r] = a2 + bed;
      pes[(sb*4 + 3)*17 + r] = a3 + bed;
      Pm[r*128 + sb*4 + 0] = p0;  Pm[r*128 + sb*4 + 1] = p1;
      Pm[r*128 + sb*4 + 2] = p2;  Pm[r*128 + sb*4 + 3] = p3;
    }
  }
  __syncthreads();
  // (s4) decoder weight slices (f16, stride WS) + biases + h2(-1) publication
  for (int i = tid; i < 16*512; i += TPB){
    int r = i >> 9, j = i & 511;
    size_t o = ((size_t)(wg*16 + r))*H_ + j;
    Wh1s[r*WS + j] = f2h(in.dec_Wh1[o]);
    Ws2s[r*WS + j] = f2h(in.dec_Wi2[o] + in.dec_Wh2[o]);
    Wats[r*WS + j] = f2h(in.attn_Wh[o]);
  }
  if (tid < 16){
    int row = wg*16 + tid;
    b1s[tid] = in.dec_bi1[row] + in.dec_bh1[row];
    b2s[tid] = in.dec_bi2[row] + in.dec_bh2[row];
    bhs[tid] = in.attn_bh[row];
    Vs[tid]  = in.attn_V[row];
    float hv = gld(&w.hbuf[HPX(0, b, wg, tid)]);   // encoder final hidden
    gst(&w.h2buf[HPX(3, b, wg, tid)], hv);
  }
  if (tid == 0) scr[8] = in.attn_bV[0];
  cbar(slots, wg, ++bt);
  const float bVv = scr[8];

  // ---- bootstrap: partials(-1) into slot 3 ----
  {
    pollgather_dual(&w.h2buf[HPB(3, b)], xv2h, fH);
    __syncthreads();
    if (tid == 0) stsflag(fH, 0.f);
    int r = tid >> 4, sl = tid & 15;
    float acc = 0.f;
    #pragma unroll
    for (int k = 0; k < 16; k++){
      int jj = sl + 16*k;
      acc = dot2h(*(const half2v*)&Wats[r*WS + 2*jj], xv2h[jj], acc);
    }
    acc = red16(acc);
    if (sl == 0) qs[r] = acc + bhs[r];
    __syncthreads();
    if (tid < 128){
      float part = 0.f;
      #pragma unroll
      for (int di = 0; di < 16; di++)
        part += Vs[di] * ftanh(pes[tid*17 + di] + qs[di]);
      gst(&w.partials[PPX(3, b, wg, tid)], part);
    }
  }
  cbar(slots, wg, ++bt);

  // ---- decoder main loop: R7 protocol, staggered polls, q-first ----
  const int r = tid >> 4, sl = tid & 15;
  for (int t = 0; t < SD_; t++){
    const int sA = (t+3)&3;     // gen t-1 slot (h2, partials)
    const int sB = t&3;         // gen t slot (h1, h2)
    const int sP = (t+1)&3;     // slot to poison
    // ===== P13 =====
    float xepre = w.xe[((size_t)b*SD_ + t)*H_ + wg*16 + r];   // prefetch
    pollgather_dual(&w.h2buf[HPB(sA, b)], xv2h, fH);
    __syncthreads();                       // join
    if (tid == 0) stsflag(fH, 0.f);        // next fH use >=2 syncs away
    {   // q matvec first (shortest path to the partials rendezvous)
      float aq = 0.f;
      #pragma unroll
      for (int k = 0; k < 16; k++){
        int jj = sl + 16*k;
        aq = dot2h(*(const half2v*)&Wats[r*WS + 2*jj], xv2h[jj], aq);
      }
      aq = red16(aq);
      if (sl == 0) qs[r] = aq + bhs[r];
    }
    __syncthreads();
    // publish partials ASAP
    if (tid < 128){
      float part = 0.f;
      #pragma unroll
      for (int di = 0; di < 16; di++)
        part += Vs[di] * ftanh(pes[tid*17 + di] + qs[di]);
      gst(&w.partials[PPX(sA, b, wg, tid)], part);
    }
    // ah = Wh1.h2 computed DURING the partials flight
    float ah = 0.f;
    #pragma unroll
    for (int k = 0; k < 16; k++){
      int jj = sl + 16*k;
      ah = dot2h(*(const half2v*)&Wh1s[r*WS + 2*jj], xv2h[jj], ah);
    }
    // partials rendezvous: all 4 waves gather the FULL 128 cols, staggered.
    // Winner writes all 128 es before setting fP (single-wave LDS ordering).
    {
      const int wv2 = tid >> 6, l2 = tid & 63;
      if (wv2 == 1)      __builtin_amdgcn_s_sleep(6);
      else if (wv2 == 2) __builtin_amdgcn_s_sleep(12);
      else if (wv2 == 3) __builtin_amdgcn_s_sleep(18);
      const float* pb = &w.partials[PPB(sA, b)];
      for (;;){
        if (ldsflag(fP) != 0.f) break;
        bool ok = true; float sumA = bVv, sumB = bVv;
        #pragma unroll
        for (int k = 0; k < 32; k++){
          float xA = gld(pb + k*128 + l2);
          float xB = gld(pb + k*128 + 64 + l2);
          ok = ok & !issent(xA) & !issent(xB);
          sumA += xA; sumB += xB;
        }
        if (__all(ok)){
          es[l2]      = __expf(sumA);
          es[l2 + 64] = __expf(sumB);
          asm volatile("s_waitcnt lgkmcnt(0)" ::: "memory");
          if (l2 == 0) stsflag(fP, 1.f);
          break;
        }
        __builtin_amdgcn_s_sleep(1);
      }
    }
    __syncthreads();                       // join: es complete
    if (tid == 0) stsflag(fP, 0.f);        // next fP use >=2 syncs away
    // denominator (wave0, post-join)
    if (tid < 64){
      float d = es[tid] + es[tid + 64];
      d += __shfl_xor(d, 1);  d += __shfl_xor(d, 2);  d += __shfl_xor(d, 4);
      d += __shfl_xor(d, 8);  d += __shfl_xor(d, 16); d += __shfl_xor(d, 32);
      if (tid == 0) scr[0] = d;
    }
    __syncthreads();
    {
      float rden = 1.f / scr[0];
      float accP = 0.f;
      #pragma unroll
      for (int k = 0; k < 8; k++){
        int s = sl + 16*k;
        accP += Pm[r*128 + s] * es[s];
      }
      float tot = red16(ah + accP*rden);
      if (sl == 0){
        int row = wg*16 + r;
        float h1v = ftanh(tot + xepre + b1s[r]);
        gst(&w.h1buf[HPX(sB, b, wg, r)], h1v);
        gst(&w.h2buf[HPX(sP, b, wg, r)], sentf());       // poison h2 slot t+1
      }
      if (tid < 128)
        gst(&w.partials[PPX(sP, b, wg, tid)], sentf());  // poison partials t+1
    }
    // ===== P2 =====
    pollgather_dual(&w.h1buf[HPB(sB, b)], xvh, fH);
    __syncthreads();                       // join
    if (tid == 0) stsflag(fH, 0.f);        // trailing step sync orders it
    {
      float acc = 0.f;
      #pragma unroll
      for (int k = 0; k < 16; k++){
        int jj = sl + 16*k;
        acc = dot2h(*(const half2v*)&Ws2s[r*WS + 2*jj], xvh[jj], acc);
      }
      acc = red16(acc);
      if (sl == 0){
        float h2v = ftanh(acc + b2s[r]);
        int row = wg*16 + r;
        gst(&w.h2buf[HPX(sB, b, wg, r)], h2v);
        w.h2all[((size_t)(b*SD_ + t))*H_ + row] = f2b(h2v);   // cross-kernel only
        gst(&w.h1buf[HPX((t+2)&3, b, wg, r)], sentf());       // poison h1 slot t+2
      }
    }
    asm volatile("s_waitcnt vmcnt(0)" ::: "memory");   // poisons before next-step stores
    __syncthreads();
  }
}

// ---------------- out_W fp32 -> bf16 ----------------
__global__ void cvt_bf16(const float* __restrict__ src, u16* __restrict__ dst, int n4){
  int idx = blockIdx.x*blockDim.x + threadIdx.x;
  int stride = gridDim.x*blockDim.x;
  for (int i = idx; i < n4; i += stride){
    float4 v = ((const float4*)src)[i];
    ushort4 o;
    o.x = f2b(v.x); o.y = f2b(v.y); o.z = f2b(v.z); o.w = f2b(v.w);
    ((ushort4*)dst)[i] = o;
  }
}

// ---------------- output projection GEMM: [2048,512] x [32000,512]^T + bias ----------------
__global__ __launch_bounds__(256, 1) void out_gemm(const u16* __restrict__ A,
    const u16* __restrict__ Bw, const float* __restrict__ bias, float* __restrict__ out)
{
  __shared__ u16 Al[128*32];
  __shared__ u16 Bl[128*32];
  int tid = threadIdx.x;
  int bidm = blockIdx.x & 15, bidn = blockIdx.x >> 4;
  int m0 = bidm*128, n0 = bidn*128;
  int wv = tid >> 6, l = tid & 63;
  int wm = wv >> 1, wn = wv & 1;
  f32x4 acc[4][4] = {};
  for (int k0 = 0; k0 < 512; k0 += 32){
    __syncthreads();
    #pragma unroll
    for (int rd = 0; rd < 2; rd++){
      int ci = rd*256 + wv*64 + l;
      int row = ci >> 2, qq = ci & 3;
      const u16* ga = A  + (size_t)(m0 + row)*512 + k0 + qq*8;
      const u16* gb = Bw + (size_t)(n0 + row)*512 + k0 + qq*8;
      __builtin_amdgcn_global_load_lds((const __attribute__((address_space(1))) unsigned int*)ga,
          (__attribute__((address_space(3))) unsigned int*)(Al + (rd*256 + wv*64)*8), 16, 0, 0);
      __builtin_amdgcn_global_load_lds((const __attribute__((address_space(1))) unsigned int*)gb,
          (__attribute__((address_space(3))) unsigned int*)(Bl + (rd*256 + wv*64)*8), 16, 0, 0);
    }
    __syncthreads();
    short8 af[4], bf[4];
    int lr = l & 15, lk = l >> 4;
    #pragma unroll
    for (int mi = 0; mi < 4; mi++)
      af[mi] = *(const short8*)(Al + (size_t)(wm*64 + mi*16 + lr)*32 + lk*8);
    #pragma unroll
    for (int ni = 0; ni < 4; ni++)
      bf[ni] = *(const short8*)(Bl + (size_t)(wn*64 + ni*16 + lr)*32 + lk*8);
    #pragma unroll
    for (int mi = 0; mi < 4; mi++)
      #pragma unroll
      for (int ni = 0; ni < 4; ni++)
        acc[mi][ni] = __builtin_amdgcn_mfma_f32_16x16x32_bf16(af[mi], bf[ni], acc[mi][ni], 0, 0, 0);
  }
  #pragma unroll
  for (int ni = 0; ni < 4; ni++){
    int col = n0 + wn*64 + ni*16 + (l & 15);
    float bb = bias[col];
    #pragma unroll
    for (int mi = 0; mi < 4; mi++){
      int row = m0 + wm*64 + mi*16 + (l >> 4)*4;
      #pragma unroll
      for (int r = 0; r < 4; r++)
        out[(size_t)(row + r)*32000 + col] = acc[mi][ni][r] + bb;
    }
  }
}

// ---------------- host ----------------
extern "C" void kernel_launch(void* const* d_in, const int* in_sizes, int n_in,
                              void* d_out, int out_size, void* d_ws, size_t ws_size,
                              hipStream_t stream)
{
  (void)in_sizes; (void)n_in; (void)out_size; (void)ws_size;
  Inputs in;
  in.enc_input = (const int*)d_in[0];
  in.target    = (const int*)d_in[1];
  in.enc_emb   = (const float*)d_in[2];
  in.enc_Wi1   = (const float*)d_in[3];  in.enc_bi1 = (const float*)d_in[4];
  in.enc_Wh1   = (const float*)d_in[5];  in.enc_bh1 = (const float*)d_in[6];
  in.enc_Wi2   = (const float*)d_in[7];  in.enc_bi2 = (const float*)d_in[8];
  in.enc_Wh2   = (const float*)d_in[9];  in.enc_bh2 = (const float*)d_in[10];
  in.dec_emb   = (const float*)d_in[11];
  in.attn_We   = (const float*)d_in[12]; in.attn_be = (const float*)d_in[13];
  in.attn_Wh   = (const float*)d_in[14]; in.attn_bh = (const float*)d_in[15];
  in.attn_V    = (const float*)d_in[16]; in.attn_bV = (const float*)d_in[17];
  in.dec_Wi1   = (const float*)d_in[18]; in.dec_bi1 = (const float*)d_in[19];
  in.dec_Wh1   = (const float*)d_in[20]; in.dec_bh1 = (const float*)d_in[21];
  in.dec_Wi2   = (const float*)d_in[22]; in.dec_bi2 = (const float*)d_in[23];
  in.dec_Wh2   = (const float*)d_in[24]; in.dec_bh2 = (const float*)d_in[25];
  in.out_W     = (const float*)d_in[26]; in.out_b   = (const float*)d_in[27];

  char* ws = (char*)d_ws;
  char* od = (char*)d_out;
  Wksp w;
  w.bar      = (u32*)ws;                      // 1 KB (memset each call)
  w.hbuf     = (float*)(ws + 1024);           // packed [4][8][32][16]
  w.h1buf    = (float*)(ws + 66560);          // packed [4][8][32][16]
  w.h2buf    = (float*)(ws + 132096);         // packed [4][8][32][16]
  w.partials = (float*)(ws + 197632);         // packed [4][8][32][128]
  w.h2all    = (u16*)  (ws + 721920);         // [2048][512] bf16
  w.wb       = (u16*)  (ws + 2819072);        // [32000][512] bf16
  w.xi1    = (float*)(od);
  w.xi2    = (float*)(od + (1 << 21));
  w.out1   = (float*)(od + 2*(1 << 21));
  w.encout = (float*)(od + 3*(1 << 21));
  w.xe     = (float*)(od + 4*(1 << 21));      // [8][256][512] f32

  hipMemsetAsync(d_ws, 0, 1024, stream);
  cvt_bf16<<<dim3(4096), dim3(256), 0, stream>>>(in.out_W, w.wb, 32000*512/4);
  seq2seq_persist<<<dim3(256), dim3(TPB), 0, stream>>>(in, w);
  out_gemm<<<dim3(4000), dim3(256), 0, stream>>>(w.h2all, w.wb, in.out_b, (float*)d_out);
}

// Round 11
// 2831.019 us; speedup vs baseline: 1.0489x; 1.0489x over previous
//
#include <hip/hip_runtime.h>

#define TPB 256
#define NWG 32
#define B_  8
#define H_  512
#define E_  256
#define SE_ 128
#define SD_ 256
#define WS  530   // f16 weight row stride (u16 units), even -> 4B aligned pairs

typedef unsigned short u16;
typedef unsigned int   u32;
typedef __attribute__((ext_vector_type(4))) float f32x4;
typedef __attribute__((ext_vector_type(8))) short short8;
typedef __attribute__((ext_vector_type(2))) _Float16 half2v;

#define SENTU 0x7FC00001u

// ---------------- numeric helpers ----------------
__device__ __forceinline__ u16 f2b(float f){
  u32 u = __float_as_uint(f);
  u = (u + 0x7fffu + ((u >> 16) & 1u)) >> 16;   // RNE f32->bf16
  return (u16)u;
}
__device__ __forceinline__ u16 f2h(float f){
  _Float16 h = (_Float16)f;
  return __builtin_bit_cast(unsigned short, h);
}
__device__ __forceinline__ void b2f2(u32 p, float& a, float& b){
  a = __uint_as_float(p << 16);
  b = __uint_as_float(p & 0xffff0000u);
}
__device__ __forceinline__ float ftanh(float x){
  float e = __expf(2.f * x);
  return 1.f - 2.f / (e + 1.f);
}
__device__ __forceinline__ float red16(float v){
  v += __shfl_xor(v, 1); v += __shfl_xor(v, 2);
  v += __shfl_xor(v, 4); v += __shfl_xor(v, 8);
  return v;
}
__device__ __forceinline__ float sentf(){ return __uint_as_float(SENTU); }
__device__ __forceinline__ bool issent(float x){ return __float_as_uint(x) == SENTU; }
__device__ __forceinline__ float dot2h(half2v w, half2v x, float acc){
#if __has_builtin(__builtin_amdgcn_fdot2)
  return __builtin_amdgcn_fdot2(w, x, acc, false);
#else
  return acc + (float)w.x * (float)x.x + (float)w.y * (float)x.y;
#endif
}

// Coherent primitives (proven R3/R7): relaxed agent-scope atomics = sc0 sc1 ops.
__device__ __forceinline__ float gld(const float* p){
  return __hip_atomic_load(p, __ATOMIC_RELAXED, __HIP_MEMORY_SCOPE_AGENT);
}
__device__ __forceinline__ void gst(float* p, float v){
  __hip_atomic_store(p, v, __ATOMIC_RELAXED, __HIP_MEMORY_SCOPE_AGENT);
}

// packed-publication indexing (R7)
__device__ __forceinline__ int HPX(int slot,int b,int wg,int r){ return ((slot*8+b)*32+wg)*16+r; }
__device__ __forceinline__ int HPB(int slot,int b){ return (slot*8+b)*512; }
__device__ __forceinline__ int PPX(int slot,int b,int wg,int s){ return ((slot*8+b)*32+wg)*128+s; }
__device__ __forceinline__ int PPB(int slot,int b){ return (slot*8+b)*4096; }

// poll-gather 512-f32 publication block via dwordx4 sc0 sc1 (R9, proven).
// tid<128 poll+stage to LDS as half pairs; waves 2-3 idle (join at caller).
__device__ __forceinline__ void pollgather_h(const float* base, half2v* dsth){
  const int tid = threadIdx.x;
  if (tid < 128){
    const float* p = base + tid*4;
    f32x4 v;
    for (;;){
      asm volatile("global_load_dwordx4 %0, %1, off sc0 sc1\n\ts_waitcnt vmcnt(0)"
                   : "=v"(v) : "v"(p) : "memory");
      bool ok = !issent(v.x) && !issent(v.y) && !issent(v.z) && !issent(v.w);
      if (__all(ok)) break;
      __builtin_amdgcn_s_sleep(1);
    }
    half2v h0, h1;
    h0.x = (_Float16)v.x; h0.y = (_Float16)v.y;
    h1.x = (_Float16)v.z; h1.y = (_Float16)v.w;
    dsth[tid*2]     = h0;
    dsth[tid*2 + 1] = h1;
  }
}
// zero-cost drain point: waves 2-3 ack their outstanding stores while waves
// 0-1 poll (they'd be idling at the join barrier anyway). Orders poisons
// before the same thread's future real store to the same slot.
__device__ __forceinline__ void drain_hi(){
  if (threadIdx.x >= 128) asm volatile("s_waitcnt vmcnt(0)" ::: "memory");
}

// ---------------- params ----------------
struct Inputs {
  const int   *enc_input, *target;
  const float *enc_emb;
  const float *enc_Wi1, *enc_bi1, *enc_Wh1, *enc_bh1;
  const float *enc_Wi2, *enc_bi2, *enc_Wh2, *enc_bh2;
  const float *dec_emb;
  const float *attn_We, *attn_be, *attn_Wh, *attn_bh, *attn_V, *attn_bV;
  const float *dec_Wi1, *dec_bi1, *dec_Wh1, *dec_bh1;
  const float *dec_Wi2, *dec_bi2, *dec_Wh2, *dec_bh2;
  const float *out_W, *out_b;
};
struct Wksp {
  u32*  bar;
  float *hbuf, *h1buf, *h2buf, *partials;  // packed 4-slot sentinel buffers (R7)
  float *xi1, *xi2, *out1, *encout, *xe;   // live in d_out (consumed pre-GEMM)
  u16   *h2all, *wb;
};

// ---------------- LDS layout (bytes) ----------------
constexpr int OFF_A   = 0;        // dec: Wh1s f16[16][530] | enc: WaE
constexpr int OFF_A2  = 17024;    // dec: Ws2s f16[16][530] | enc: WbE (scan, f16)
constexpr int OFF_A3  = 34048;    // dec: Wats f16[16][530] | enc: 16KB staging
constexpr int OFF_PM  = 51008;    // f32 [16][128]  P matrix
constexpr int OFF_PES = 59200;    // f32 [128][17]  pe slice (padded)
constexpr int OFF_STG = 67904;    // f32 [2048]     setup staging
constexpr int OFF_WRG = 76096;    // f32 [16][768]  Wi1 own rows (setup)
constexpr int OFF_XVH = 125248;   // half[512]  (P2 h1 vector / enc even-t)
constexpr int OFF_XV2H= 126272;   // half[512]  (P13 h2 vector / enc odd-t)
constexpr int OFF_ES  = 127296;   // f32 [128]
constexpr int OFF_QS  = 127808;   // f32 [16]
constexpr int OFF_VS  = 127872;   // f32 [16]
constexpr int OFF_B1  = 127936;
constexpr int OFF_B2  = 128000;
constexpr int OFF_BH  = 128064;
constexpr int OFF_BSC = 128128;
constexpr int OFF_SCR = 128192;   // f32 [16]
constexpr int LDS_BYTES = 128256;

// ---------------- stage barrier (proven R3) ----------------
__device__ __forceinline__ void cbar(u32* slots, int wg, u32 target){
  asm volatile("s_waitcnt vmcnt(0)" ::: "memory");
  __syncthreads();
  const int tid = threadIdx.x;
  if (tid < 64){
    if (tid == 0)
      __hip_atomic_store(&slots[wg], target, __ATOMIC_RELAXED, __HIP_MEMORY_SCOPE_AGENT);
    bool done = false;
    do {
      u32 v = __hip_atomic_load(&slots[tid & 31], __ATOMIC_RELAXED, __HIP_MEMORY_SCOPE_AGENT);
      done = (v >= target);
    } while (__ballot(done) != ~0ull);
  }
  __syncthreads();
  asm volatile("" ::: "memory");
}

// ---------------- encoder scan: R7 sentinel dataflow, f16 compute ----------------
// Trailing per-step vmcnt+sync removed: waves 0-1 drain inside next poll;
// waves 2-3 drain via drain_hi() while 0-1 poll. Staging buffer alternates
// by parity so the poll's LDS write never races prior-step reads.
__device__ void enc_scan(const Wksp& w,
                         const float* __restrict__ Wh, const float* __restrict__ bh,
                         const float* __restrict__ xi, float* __restrict__ outbuf,
                         int b, int wg, u16* WbE, half2v* xvA, half2v* xvB, float* bscan)
{
  const int tid = threadIdx.x;
  for (int i = tid; i < 16*512; i += TPB){
    int r = i >> 9, j = i & 511;
    WbE[r*WS + j] = f2h(Wh[((size_t)(wg*16 + r))*H_ + j]);
  }
  if (tid < 16) bscan[tid] = bh[wg*16 + tid];
  __syncthreads();
  for (int t = 0; t < SE_; t++){
    half2v* xb = (t & 1) ? xvB : xvA;
    drain_hi();
    pollgather_h(&w.hbuf[HPB(t&3, b)], xb);
    __syncthreads();
    int r = tid >> 4, sl = tid & 15;
    float acc = 0.f;
    #pragma unroll
    for (int k = 0; k < 16; k++){
      int jj = sl + 16*k;
      acc = dot2h(*(const half2v*)&WbE[r*WS + 2*jj], xb[jj], acc);
    }
    acc = red16(acc);
    if (sl == 0){
      int row = wg*16 + r;
      float hv = ftanh(xi[((size_t)b*SE_ + t)*H_ + row] + acc + bscan[r]);
      gst(&w.hbuf[HPX((t+1)&3, b, wg, r)], hv);          // publish (1 packed line)
      gst(&outbuf[((size_t)b*SE_ + t)*H_ + row], hv);    // bulk history
      gst(&w.hbuf[HPX((t+3)&3, b, wg, r)], sentf());     // poison (reads done 2 steps ago)
    }
    // no trailing vmcnt/sync: next step's drain_hi + poll-join provide both
  }
}

// ---------------- persistent seq2seq kernel ----------------
__global__ __launch_bounds__(TPB, 1) void seq2seq_persist(Inputs in, Wksp w)
{
  __shared__ __attribute__((aligned(16))) unsigned char S[LDS_BYTES];
  u16* Wh1s = (u16*)(S + OFF_A);
  u16* Ws2s = (u16*)(S + OFF_A2);
  u16* Wats = (u16*)(S + OFF_A3);
  u16* WaE  = (u16*)(S + OFF_A);    // encoder aliases
  u16* WbE  = (u16*)(S + OFF_A2);
  float* stgE = (float*)(S + OFF_A3);
  float* Pm   = (float*)(S + OFF_PM);
  float* pes  = (float*)(S + OFF_PES);
  float* STG  = (float*)(S + OFF_STG);
  float* WRG  = (float*)(S + OFF_WRG);
  half2v* xvh  = (half2v*)(S + OFF_XVH);
  half2v* xv2h = (half2v*)(S + OFF_XV2H);
  float* es   = (float*)(S + OFF_ES);
  float* qs   = (float*)(S + OFF_QS);
  float* Vs   = (float*)(S + OFF_VS);
  float* b1s  = (float*)(S + OFF_B1);
  float* b2s  = (float*)(S + OFF_B2);
  float* bhs  = (float*)(S + OFF_BH);
  float* bscan= (float*)(S + OFF_BSC);
  float* scr  = (float*)(S + OFF_SCR);

  const int bid = blockIdx.x;
  const int c = bid & 7, wg = bid >> 3;   // cluster = batch, 32 WGs
  const int b = c;
  const int tid = threadIdx.x;
  u32* slots = w.bar + c*32;
  u32 bt = 0;

  // ---- initial state: h0 real (packed), other rotation slots poisoned ----
  if (tid < 16){
    gst(&w.hbuf[HPX(0, b, wg, tid)], 0.f);
    #pragma unroll
    for (int s2 = 1; s2 < 4; s2++) gst(&w.hbuf[HPX(s2, b, wg, tid)], sentf());
    #pragma unroll
    for (int s2 = 0; s2 < 4; s2++) gst(&w.h1buf[HPX(s2, b, wg, tid)], sentf());
    #pragma unroll
    for (int s2 = 0; s2 < 3; s2++) gst(&w.h2buf[HPX(s2, b, wg, tid)], sentf());
  }
  if (tid < 128){
    #pragma unroll
    for (int s2 = 0; s2 < 3; s2++) gst(&w.partials[PPX(s2, b, wg, tid)], sentf());
  }

  // ---- encoder layer1 input GEMM (xi1 = emb @ Wi1^T + bi1), WG-private ----
  for (int i = tid; i < 16*256; i += TPB){
    int r = i >> 8, j = i & 255;
    WaE[r*264 + j] = f2b(in.enc_Wi1[((size_t)(wg*16 + r))*E_ + j]);
  }
  if (tid < 16) bscan[tid] = in.enc_bi1[wg*16 + tid];
  __syncthreads();
  for (int k0 = 0; k0 < 8; k0++){
    for (int it = 0; it < 16; it++){
      int tok = in.enc_input[b*SE_ + k0*16 + it];
      stgE[it*256 + tid] = in.enc_emb[(size_t)tok*E_ + tid];
    }
    __syncthreads();
    int r = tid & 15, tt = tid >> 4;
    float acc = 0.f;
    #pragma unroll 16
    for (int j = 0; j < 256; j += 2){
      u32 p = *(const u32*)&WaE[r*264 + j];
      float w0, w1; b2f2(p, w0, w1);
      float2 x = *(const float2*)&stgE[tt*256 + j];
      acc += w0*x.x + w1*x.y;
    }
    w.xi1[((size_t)b*SE_ + k0*16 + tt)*H_ + wg*16 + r] = acc + bscan[r];
    __syncthreads();
  }
  cbar(slots, wg, ++bt);

  // ---- encoder layer1 scan ----
  enc_scan(w, in.enc_Wh1, in.enc_bh1, w.xi1, w.out1, b, wg, WbE, xvh, xv2h, bscan);
  cbar(slots, wg, ++bt);

  // ---- xi2 = out1 @ Wi2^T + bi2 ; re-poison hbuf slots 1..3 for L2 scan ----
  for (int i = tid; i < 16*512; i += TPB){
    int r = i >> 9, j = i & 511;
    WaE[r*522 + j] = f2b(in.enc_Wi2[((size_t)(wg*16 + r))*H_ + j]);
  }
  if (tid < 16){
    bscan[tid] = in.enc_bi2[wg*16 + tid];
    #pragma unroll
    for (int s2 = 1; s2 < 4; s2++) gst(&w.hbuf[HPX(s2, b, wg, tid)], sentf());
  }
  __syncthreads();
  {
    u16* stg2 = (u16*)stgE;
    for (int k0 = 0; k0 < 8; k0++){
      for (int it = 0; it < 16; it++){
        size_t base = ((size_t)b*SE_ + k0*16 + it)*H_;
        stg2[it*512 + tid]       = f2b(gld(&w.out1[base + tid]));
        stg2[it*512 + tid + 256] = f2b(gld(&w.out1[base + tid + 256]));
      }
      __syncthreads();
      int r = tid & 15, tt = tid >> 4;
      float acc = 0.f;
      #pragma unroll 16
      for (int j = 0; j < 512; j += 2){
        u32 p  = *(const u32*)&WaE[r*522 + j];
        u32 s2 = *(const u32*)&stg2[tt*512 + j];
        float w0, w1, s0, s1; b2f2(p, w0, w1); b2f2(s2, s0, s1);
        acc += w0*s0 + w1*s1;
      }
      w.xi2[((size_t)b*SE_ + k0*16 + tt)*H_ + wg*16 + r] = acc + bscan[r];
      __syncthreads();
    }
  }
  cbar(slots, wg, ++bt);

  // ---- encoder layer2 scan (initial hidden = L1 final, already in slot 0) ----
  enc_scan(w, in.enc_Wh2, in.enc_bh2, w.xi2, w.encout, b, wg, WbE, xvh, xv2h, bscan);
  cbar(slots, wg, ++bt);

  // ======== decoder setup ========
  for (int i = tid; i < 16*768; i += TPB)
    WRG[i] = in.dec_Wi1[(size_t)(wg*16 + i/768)*768 + (i - (i/768)*768)];
  for (int tb = 0; tb < 32; tb++){
    __syncthreads();
    for (int i = tid; i < 8*256; i += TPB){
      int tt = tb*8 + (i >> 8);
      int tok = in.target[b*SD_ + (tt == 0 ? 0 : tt - 1)];
      STG[i] = in.dec_emb[(size_t)tok*E_ + (i & 255)];
    }
    __syncthreads();
    int r = tid >> 4, sl = tid & 15;
    for (int t2 = 0; t2 < 8; t2++){
      float acc = 0.f;
      #pragma unroll
      for (int k = 0; k < 8; k++){
        int j = 2*sl + 32*k;
        float2 wv = *(const float2*)&WRG[r*768 + j];
        float2 xx = *(const float2*)&STG[t2*256 + j];
        acc += wv.x*xx.x + wv.y*xx.y;
      }
      acc = red16(acc);
      if (sl == 0) w.xe[((size_t)b*SD_ + tb*8 + t2)*H_ + wg*16 + r] = acc;
    }
  }
  for (int sb = 0; sb < 32; sb++){
    __syncthreads();
    for (int i = tid; i < 4*512; i += TPB)
      STG[i] = gld(&w.encout[((size_t)b*SE_ + sb*4 + (i >> 9))*H_ + (i & 511)]);
    __syncthreads();
    int r = tid >> 4, sl = tid & 15;
    const float* wer = in.attn_We + (size_t)(wg*16 + r)*H_;
    float a0=0.f, a1=0.f, a2=0.f, a3=0.f;
    float p0=0.f, p1=0.f, p2=0.f, p3=0.f;
    #pragma unroll
    for (int k = 0; k < 16; k++){
      int j = 2*sl + 32*k;
      float2 wv = *(const float2*)&wer[j];
      float2 x0 = *(const float2*)&STG[j];
      float2 x1 = *(const float2*)&STG[512 + j];
      float2 x2 = *(const float2*)&STG[1024 + j];
      float2 x3 = *(const float2*)&STG[1536 + j];
      a0 += wv.x*x0.x + wv.y*x0.y;  a1 += wv.x*x1.x + wv.y*x1.y;
      a2 += wv.x*x2.x + wv.y*x2.y;  a3 += wv.x*x3.x + wv.y*x3.y;
      float2 cv = *(const float2*)&WRG[r*768 + 256 + j];
      p0 += cv.x*x0.x + cv.y*x0.y;  p1 += cv.x*x1.x + cv.y*x1.y;
      p2 += cv.x*x2.x + cv.y*x2.y;  p3 += cv.x*x3.x + cv.y*x3.y;
    }
    a0 = red16(a0); a1 = red16(a1); a2 = red16(a2); a3 = red16(a3);
    p0 = red16(p0); p1 = red16(p1); p2 = red16(p2); p3 = red16(p3);
    if (sl == 0){
      float bed = in.attn_be[wg*16 + r];
      pes[(sb*4 + 0)*17 + r] = a0 + bed;
      pes[(sb*4 + 1)*17 + r] = a1 + bed;
      pes[(sb*4 + 2)*17 + r] = a2 + bed;
      pes[(sb*4 + 3)*17 + r] = a3 + bed;
      Pm[r*128 + sb*4 + 0] = p0;  Pm[r*128 + sb*4 + 1] = p1;
      Pm[r*128 + sb*4 + 2] = p2;  Pm[r*128 + sb*4 + 3] = p3;
    }
  }
  __syncthreads();
  // (s4) decoder weight slices (f16, stride WS) + biases + h2(-1) publication
  for (int i = tid; i < 16*512; i += TPB){
    int r = i >> 9, j = i & 511;
    size_t o = ((size_t)(wg*16 + r))*H_ + j;
    Wh1s[r*WS + j] = f2h(in.dec_Wh1[o]);
    Ws2s[r*WS + j] = f2h(in.dec_Wi2[o] + in.dec_Wh2[o]);
    Wats[r*WS + j] = f2h(in.attn_Wh[o]);
  }
  if (tid < 16){
    int row = wg*16 + tid;
    b1s[tid] = in.dec_bi1[row] + in.dec_bh1[row];
    b2s[tid] = in.dec_bi2[row] + in.dec_bh2[row];
    bhs[tid] = in.attn_bh[row];
    Vs[tid]  = in.attn_V[row];
    float hv = gld(&w.hbuf[HPX(0, b, wg, tid)]);   // encoder final hidden
    gst(&w.h2buf[HPX(3, b, wg, tid)], hv);
  }
  if (tid == 0) scr[8] = in.attn_bV[0];
  cbar(slots, wg, ++bt);
  const float bVv = scr[8];

  // ---- bootstrap: partials(-1) into slot 3 ----
  {
    pollgather_h(&w.h2buf[HPB(3, b)], xv2h);
    __syncthreads();
    int r = tid >> 4, sl = tid & 15;
    float acc = 0.f;
    #pragma unroll
    for (int k = 0; k < 16; k++){
      int jj = sl + 16*k;
      acc = dot2h(*(const half2v*)&Wats[r*WS + 2*jj], xv2h[jj], acc);
    }
    acc = red16(acc);
    if (sl == 0) qs[r] = acc + bhs[r];
    __syncthreads();
    if (tid < 128){
      float part = 0.f;
      #pragma unroll
      for (int di = 0; di < 16; di++)
        part += Vs[di] * ftanh(pes[tid*17 + di] + qs[di]);
      gst(&w.partials[PPX(3, b, wg, tid)], part);
    }
  }
  cbar(slots, wg, ++bt);

  // ---- decoder main loop: R9 structure, end-of-step drain/sync removed ----
  const int r = tid >> 4, sl = tid & 15;
  for (int t = 0; t < SD_; t++){
    const int sA = (t+3)&3;     // gen t-1 slot (h2, partials)
    const int sB = t&3;         // gen t slot (h1, h2)
    const int sP = (t+1)&3;     // slot to poison
    // ===== P13 =====
    float xepre = w.xe[((size_t)b*SD_ + t)*H_ + wg*16 + r];   // prefetch
    drain_hi();                                // waves 2-3: ack prior-step stores
    pollgather_h(&w.h2buf[HPB(sA, b)], xv2h);  // waves 0-1: poll (self-drains)
    __syncthreads();
    {   // q matvec first (shortest path to the partials rendezvous)
      float aq = 0.f;
      #pragma unroll
      for (int k = 0; k < 16; k++){
        int jj = sl + 16*k;
        aq = dot2h(*(const half2v*)&Wats[r*WS + 2*jj], xv2h[jj], aq);
      }
      aq = red16(aq);
      if (sl == 0) qs[r] = aq + bhs[r];
    }
    __syncthreads();
    // publish partials ASAP
    if (tid < 128){
      float part = 0.f;
      #pragma unroll
      for (int di = 0; di < 16; di++)
        part += Vs[di] * ftanh(pes[tid*17 + di] + qs[di]);
      gst(&w.partials[PPX(sA, b, wg, tid)], part);
    }
    // ah = Wh1.h2 computed DURING the partials flight
    float ah = 0.f;
    #pragma unroll
    for (int k = 0; k < 16; k++){
      int jj = sl + 16*k;
      ah = dot2h(*(const half2v*)&Wh1s[r*WS + 2*jj], xv2h[jj], ah);
    }
    // partials allgather + softmax (batched reload per round, R7-style)
    if (tid < 128){
      const float* pb = &w.partials[PPB(sA, b)];
      float sum;
      for (;;){
        bool ok = true; sum = bVv;
        #pragma unroll
        for (int k = 0; k < 32; k++){
          float x = gld(pb + k*128 + tid);
          ok = ok && !issent(x);
          sum += x;
        }
        if (__all(ok)) break;
        __builtin_amdgcn_s_sleep(1);
      }
      float e = __expf(sum);
      es[tid] = e;
      float d = e;
      d += __shfl_xor(d, 1);  d += __shfl_xor(d, 2);  d += __shfl_xor(d, 4);
      d += __shfl_xor(d, 8);  d += __shfl_xor(d, 16); d += __shfl_xor(d, 32);
      if ((tid & 63) == 0) scr[tid >> 6] = d;
    }
    __syncthreads();
    {
      float rden = 1.f / (scr[0] + scr[1]);
      float accP = 0.f;
      #pragma unroll
      for (int k = 0; k < 8; k++){
        int s = sl + 16*k;
        accP += Pm[r*128 + s] * es[s];
      }
      float tot = red16(ah + accP*rden);
      if (sl == 0){
        int row = wg*16 + r;
        float h1v = ftanh(tot + xepre + b1s[r]);
        gst(&w.h1buf[HPX(sB, b, wg, r)], h1v);
        gst(&w.h2buf[HPX(sP, b, wg, r)], sentf());       // poison h2 slot t+1
      }
      if (tid < 128)
        gst(&w.partials[PPX(sP, b, wg, tid)], sentf());  // poison partials t+1
    }
    // ===== P2 =====
    drain_hi();                                // waves 2-3: ack P13 stores
    pollgather_h(&w.h1buf[HPB(sB, b)], xvh);   // waves 0-1: poll (self-drains)
    __syncthreads();
    {
      float acc = 0.f;
      #pragma unroll
      for (int k = 0; k < 16; k++){
        int jj = sl + 16*k;
        acc = dot2h(*(const half2v*)&Ws2s[r*WS + 2*jj], xvh[jj], acc);
      }
      acc = red16(acc);
      if (sl == 0){
        float h2v = ftanh(acc + b2s[r]);
        int row = wg*16 + r;
        gst(&w.h2buf[HPX(sB, b, wg, r)], h2v);
        w.h2all[((size_t)(b*SD_ + t))*H_ + row] = f2b(h2v);   // cross-kernel only
        gst(&w.h1buf[HPX((t+2)&3, b, wg, r)], sentf());       // poison h1 slot t+2
      }
    }
    // no trailing vmcnt/sync: next step's drain_hi + poll-join provide both
  }
}

// ---------------- out_W fp32 -> bf16 ----------------
__global__ void cvt_bf16(const float* __restrict__ src, u16* __restrict__ dst, int n4){
  int idx = blockIdx.x*blockDim.x + threadIdx.x;
  int stride = gridDim.x*blockDim.x;
  for (int i = idx; i < n4; i += stride){
    float4 v = ((const float4*)src)[i];
    ushort4 o;
    o.x = f2b(v.x); o.y = f2b(v.y); o.z = f2b(v.z); o.w = f2b(v.w);
    ((ushort4*)dst)[i] = o;
  }
}

// ---------------- output projection GEMM: [2048,512] x [32000,512]^T + bias ----------------
__global__ __launch_bounds__(256, 1) void out_gemm(const u16* __restrict__ A,
    const u16* __restrict__ Bw, const float* __restrict__ bias, float* __restrict__ out)
{
  __shared__ u16 Al[128*32];
  __shared__ u16 Bl[128*32];
  int tid = threadIdx.x;
  int bidm = blockIdx.x & 15, bidn = blockIdx.x >> 4;
  int m0 = bidm*128, n0 = bidn*128;
  int wv = tid >> 6, l = tid & 63;
  int wm = wv >> 1, wn = wv & 1;
  f32x4 acc[4][4] = {};
  for (int k0 = 0; k0 < 512; k0 += 32){
    __syncthreads();
    #pragma unroll
    for (int rd = 0; rd < 2; rd++){
      int ci = rd*256 + wv*64 + l;
      int row = ci >> 2, qq = ci & 3;
      const u16* ga = A  + (size_t)(m0 + row)*512 + k0 + qq*8;
      const u16* gb = Bw + (size_t)(n0 + row)*512 + k0 + qq*8;
      __builtin_amdgcn_global_load_lds((const __attribute__((address_space(1))) unsigned int*)ga,
          (__attribute__((address_space(3))) unsigned int*)(Al + (rd*256 + wv*64)*8), 16, 0, 0);
      __builtin_amdgcn_global_load_lds((const __attribute__((address_space(1))) unsigned int*)gb,
          (__attribute__((address_space(3))) unsigned int*)(Bl + (rd*256 + wv*64)*8), 16, 0, 0);
    }
    __syncthreads();
    short8 af[4], bf[4];
    int lr = l & 15, lk = l >> 4;
    #pragma unroll
    for (int mi = 0; mi < 4; mi++)
      af[mi] = *(const short8*)(Al + (size_t)(wm*64 + mi*16 + lr)*32 + lk*8);
    #pragma unroll
    for (int ni = 0; ni < 4; ni++)
      bf[ni] = *(const short8*)(Bl + (size_t)(wn*64 + ni*16 + lr)*32 + lk*8);
    #pragma unroll
    for (int mi = 0; mi < 4; mi++)
      #pragma unroll
      for (int ni = 0; ni < 4; ni++)
        acc[mi][ni] = __builtin_amdgcn_mfma_f32_16x16x32_bf16(af[mi], bf[ni], acc[mi][ni], 0, 0, 0);
  }
  #pragma unroll
  for (int ni = 0; ni < 4; ni++){
    int col = n0 + wn*64 + ni*16 + (l & 15);
    float bb = bias[col];
    #pragma unroll
    for (int mi = 0; mi < 4; mi++){
      int row = m0 + wm*64 + mi*16 + (l >> 4)*4;
      #pragma unroll
      for (int r = 0; r < 4; r++)
        out[(size_t)(row + r)*32000 + col] = acc[mi][ni][r] + bb;
    }
  }
}

// ---------------- host ----------------
extern "C" void kernel_launch(void* const* d_in, const int* in_sizes, int n_in,
                              void* d_out, int out_size, void* d_ws, size_t ws_size,
                              hipStream_t stream)
{
  (void)in_sizes; (void)n_in; (void)out_size; (void)ws_size;
  Inputs in;
  in.enc_input = (const int*)d_in[0];
  in.target    = (const int*)d_in[1];
  in.enc_emb   = (const float*)d_in[2];
  in.enc_Wi1   = (const float*)d_in[3];  in.enc_bi1 = (const float*)d_in[4];
  in.enc_Wh1   = (const float*)d_in[5];  in.enc_bh1 = (const float*)d_in[6];
  in.enc_Wi2   = (const float*)d_in[7];  in.enc_bi2 = (const float*)d_in[8];
  in.enc_Wh2   = (const float*)d_in[9];  in.enc_bh2 = (const float*)d_in[10];
  in.dec_emb   = (const float*)d_in[11];
  in.attn_We   = (const float*)d_in[12]; in.attn_be = (const float*)d_in[13];
  in.attn_Wh   = (const float*)d_in[14]; in.attn_bh = (const float*)d_in[15];
  in.attn_V    = (const float*)d_in[16]; in.attn_bV = (const float*)d_in[17];
  in.dec_Wi1   = (const float*)d_in[18]; in.dec_bi1 = (const float*)d_in[19];
  in.dec_Wh1   = (const float*)d_in[20]; in.dec_bh1 = (const float*)d_in[21];
  in.dec_Wi2   = (const float*)d_in[22]; in.dec_bi2 = (const float*)d_in[23];
  in.dec_Wh2   = (const float*)d_in[24]; in.dec_bh2 = (const float*)d_in[25];
  in.out_W     = (const float*)d_in[26]; in.out_b   = (const float*)d_in[27];

  char* ws = (char*)d_ws;
  char* od = (char*)d_out;
  Wksp w;
  w.bar      = (u32*)ws;                      // 1 KB (memset each call)
  w.hbuf     = (float*)(ws + 1024);           // packed [4][8][32][16]
  w.h1buf    = (float*)(ws + 66560);          // packed [4][8][32][16]
  w.h2buf    = (float*)(ws + 132096);         // packed [4][8][32][16]
  w.partials = (float*)(ws + 197632);         // packed [4][8][32][128]
  w.h2all    = (u16*)  (ws + 721920);         // [2048][512] bf16
  w.wb       = (u16*)  (ws + 2819072);        // [32000][512] bf16
  w.xi1    = (float*)(od);
  w.xi2    = (float*)(od + (1 << 21));
  w.out1   = (float*)(od + 2*(1 << 21));
  w.encout = (float*)(od + 3*(1 << 21));
  w.xe     = (float*)(od + 4*(1 << 21));      // [8][256][512] f32

  hipMemsetAsync(d_ws, 0, 1024, stream);
  cvt_bf16<<<dim3(4096), dim3(256), 0, stream>>>(in.out_W, w.wb, 32000*512/4);
  seq2seq_persist<<<dim3(256), dim3(TPB), 0, stream>>>(in, w);
  out_gemm<<<dim3(4000), dim3(256), 0, stream>>>(w.h2all, w.wb, in.out_b, (float*)d_out);
}

// Round 12
// 2487.389 us; speedup vs baseline: 1.1938x; 1.1381x over previous
//
#include <hip/hip_runtime.h>

#define TPB 256
#define NWG 32
#define B_  8
#define H_  512
#define E_  256
#define SE_ 128
#define SD_ 256
#define WS  530   // f16 weight row stride (u16 units), even -> 4B aligned pairs

typedef unsigned short u16;
typedef unsigned int   u32;
typedef __attribute__((ext_vector_type(4))) float f32x4;
typedef __attribute__((ext_vector_type(8))) short short8;
typedef __attribute__((ext_vector_type(2))) _Float16 half2v;

#define SENTU 0x7FC00001u

// ---------------- numeric helpers ----------------
__device__ __forceinline__ u16 f2b(float f){
  u32 u = __float_as_uint(f);
  u = (u + 0x7fffu + ((u >> 16) & 1u)) >> 16;   // RNE f32->bf16
  return (u16)u;
}
__device__ __forceinline__ u16 f2h(float f){
  _Float16 h = (_Float16)f;
  return __builtin_bit_cast(unsigned short, h);
}
__device__ __forceinline__ void b2f2(u32 p, float& a, float& b){
  a = __uint_as_float(p << 16);
  b = __uint_as_float(p & 0xffff0000u);
}
__device__ __forceinline__ float ftanh(float x){
  float e = __expf(2.f * x);
  return 1.f - 2.f / (e + 1.f);
}
__device__ __forceinline__ float red16(float v){
  v += __shfl_xor(v, 1); v += __shfl_xor(v, 2);
  v += __shfl_xor(v, 4); v += __shfl_xor(v, 8);
  return v;
}
__device__ __forceinline__ float sentf(){ return __uint_as_float(SENTU); }
__device__ __forceinline__ bool issent(float x){ return __float_as_uint(x) == SENTU; }
__device__ __forceinline__ float dot2h(half2v w, half2v x, float acc){
#if __has_builtin(__builtin_amdgcn_fdot2)
  return __builtin_amdgcn_fdot2(w, x, acc, false);
#else
  return acc + (float)w.x * (float)x.x + (float)w.y * (float)x.y;
#endif
}

// Coherent primitives (proven R3/R7): relaxed agent-scope atomics = sc0 sc1 ops.
__device__ __forceinline__ float gld(const float* p){
  return __hip_atomic_load(p, __ATOMIC_RELAXED, __HIP_MEMORY_SCOPE_AGENT);
}
__device__ __forceinline__ void gst(float* p, float v){
  __hip_atomic_store(p, v, __ATOMIC_RELAXED, __HIP_MEMORY_SCOPE_AGENT);
}

// packed-publication indexing (R7)
__device__ __forceinline__ int HPX(int slot,int b,int wg,int r){ return ((slot*8+b)*32+wg)*16+r; }
__device__ __forceinline__ int HPB(int slot,int b){ return (slot*8+b)*512; }
__device__ __forceinline__ int PPX(int slot,int b,int wg,int s){ return ((slot*8+b)*32+wg)*128+s; }
__device__ __forceinline__ int PPB(int slot,int b){ return (slot*8+b)*4096; }

// poll-gather 512-f32 publication block via dwordx4 sc0 sc1 (same cache-op
// bits as the proven atomic loads; each dword independently sentinel-checked).
// Stages result as half pairs into LDS. Threads >=128 idle (sync at caller).
__device__ __forceinline__ void pollgather_h(const float* base, half2v* dsth){
  const int tid = threadIdx.x;
  if (tid < 128){
    const float* p = base + tid*4;
    f32x4 v;
    for (;;){
      asm volatile("global_load_dwordx4 %0, %1, off sc0 sc1\n\ts_waitcnt vmcnt(0)"
                   : "=v"(v) : "v"(p) : "memory");
      bool ok = !issent(v.x) && !issent(v.y) && !issent(v.z) && !issent(v.w);
      if (__all(ok)) break;
      __builtin_amdgcn_s_sleep(1);
    }
    half2v h0, h1;
    h0.x = (_Float16)v.x; h0.y = (_Float16)v.y;
    h1.x = (_Float16)v.z; h1.y = (_Float16)v.w;
    dsth[tid*2]     = h0;
    dsth[tid*2 + 1] = h1;
  }
}

// ---------------- params ----------------
struct Inputs {
  const int   *enc_input, *target;
  const float *enc_emb;
  const float *enc_Wi1, *enc_bi1, *enc_Wh1, *enc_bh1;
  const float *enc_Wi2, *enc_bi2, *enc_Wh2, *enc_bh2;
  const float *dec_emb;
  const float *attn_We, *attn_be, *attn_Wh, *attn_bh, *attn_V, *attn_bV;
  const float *dec_Wi1, *dec_bi1, *dec_Wh1, *dec_bh1;
  const float *dec_Wi2, *dec_bi2, *dec_Wh2, *dec_bh2;
  const float *out_W, *out_b;
};
struct Wksp {
  u32*  bar;
  float *hbuf, *h1buf, *h2buf, *partials;  // packed 4-slot sentinel buffers (R7)
  float *xi1, *xi2, *out1, *encout, *xe;   // live in d_out (consumed pre-GEMM)
  u16   *h2all, *wb;
};

// ---------------- LDS layout (bytes) ----------------
constexpr int OFF_A   = 0;        // dec: Wh1s f16[16][530] | enc: WaE
constexpr int OFF_A2  = 17024;    // dec: Ws2s f16[16][530] | enc: WbE (scan, f16)
constexpr int OFF_A3  = 34048;    // dec: Wats f16[16][530] | enc: 16KB staging
constexpr int OFF_PM  = 51008;    // f32 [16][128]  P matrix
constexpr int OFF_PES = 59200;    // f32 [128][17]  pe slice (padded)
constexpr int OFF_STG = 67904;    // f32 [2048]     setup staging
constexpr int OFF_WRG = 76096;    // f32 [16][768]  Wi1 own rows (setup)
constexpr int OFF_XVH = 125248;   // half[512]  (P2 h1 vector / enc h vector)
constexpr int OFF_XV2H= 126272;   // half[512]  (P13 h2 vector)
constexpr int OFF_ES  = 127296;   // f32 [128]
constexpr int OFF_QS  = 127808;   // f32 [16]
constexpr int OFF_VS  = 127872;   // f32 [16]
constexpr int OFF_B1  = 127936;
constexpr int OFF_B2  = 128000;
constexpr int OFF_BH  = 128064;
constexpr int OFF_BSC = 128128;
constexpr int OFF_SCR = 128192;   // f32 [16]
constexpr int LDS_BYTES = 128256;

// ---------------- stage barrier (proven R3) ----------------
__device__ __forceinline__ void cbar(u32* slots, int wg, u32 target){
  asm volatile("s_waitcnt vmcnt(0)" ::: "memory");
  __syncthreads();
  const int tid = threadIdx.x;
  if (tid < 64){
    if (tid == 0)
      __hip_atomic_store(&slots[wg], target, __ATOMIC_RELAXED, __HIP_MEMORY_SCOPE_AGENT);
    bool done = false;
    do {
      u32 v = __hip_atomic_load(&slots[tid & 31], __ATOMIC_RELAXED, __HIP_MEMORY_SCOPE_AGENT);
      done = (v >= target);
    } while (__ballot(done) != ~0ull);
  }
  __syncthreads();
  asm volatile("" ::: "memory");
}

// ---------------- encoder scan: R7 sentinel dataflow, f16 compute ----------------
__device__ void enc_scan(const Wksp& w,
                         const float* __restrict__ Wh, const float* __restrict__ bh,
                         const float* __restrict__ xi, float* __restrict__ outbuf,
                         int b, int wg, u16* WbE, half2v* xvh, float* bscan)
{
  const int tid = threadIdx.x;
  for (int i = tid; i < 16*512; i += TPB){
    int r = i >> 9, j = i & 511;
    WbE[r*WS + j] = f2h(Wh[((size_t)(wg*16 + r))*H_ + j]);
  }
  if (tid < 16) bscan[tid] = bh[wg*16 + tid];
  __syncthreads();
  for (int t = 0; t < SE_; t++){
    pollgather_h(&w.hbuf[HPB(t&3, b)], xvh);
    __syncthreads();
    int r = tid >> 4, sl = tid & 15;
    float acc = 0.f;
    #pragma unroll
    for (int k = 0; k < 16; k++){
      int jj = sl + 16*k;
      acc = dot2h(*(const half2v*)&WbE[r*WS + 2*jj], xvh[jj], acc);
    }
    acc = red16(acc);
    if (sl == 0){
      int row = wg*16 + r;
      float hv = ftanh(xi[((size_t)b*SE_ + t)*H_ + row] + acc + bscan[r]);
      gst(&w.hbuf[HPX((t+1)&3, b, wg, r)], hv);          // publish (1 packed line)
      gst(&outbuf[((size_t)b*SE_ + t)*H_ + row], hv);    // bulk history
      gst(&w.hbuf[HPX((t+3)&3, b, wg, r)], sentf());     // poison (reads done 2 steps ago)
    }
    asm volatile("s_waitcnt vmcnt(0)" ::: "memory");
    __syncthreads();
  }
}

// ---------------- persistent seq2seq kernel ----------------
__global__ __launch_bounds__(TPB, 1) void seq2seq_persist(Inputs in, Wksp w)
{
  __shared__ __attribute__((aligned(16))) unsigned char S[LDS_BYTES];
  u16* Wh1s = (u16*)(S + OFF_A);
  u16* Ws2s = (u16*)(S + OFF_A2);
  u16* Wats = (u16*)(S + OFF_A3);
  u16* WaE  = (u16*)(S + OFF_A);    // encoder aliases
  u16* WbE  = (u16*)(S + OFF_A2);
  float* stgE = (float*)(S + OFF_A3);
  float* Pm   = (float*)(S + OFF_PM);
  float* pes  = (float*)(S + OFF_PES);
  float* STG  = (float*)(S + OFF_STG);
  float* WRG  = (float*)(S + OFF_WRG);
  half2v* xvh  = (half2v*)(S + OFF_XVH);
  half2v* xv2h = (half2v*)(S + OFF_XV2H);
  float* es   = (float*)(S + OFF_ES);
  float* qs   = (float*)(S + OFF_QS);
  float* Vs   = (float*)(S + OFF_VS);
  float* b1s  = (float*)(S + OFF_B1);
  float* b2s  = (float*)(S + OFF_B2);
  float* bhs  = (float*)(S + OFF_BH);
  float* bscan= (float*)(S + OFF_BSC);
  float* scr  = (float*)(S + OFF_SCR);

  const int bid = blockIdx.x;
  const int c = bid & 7, wg = bid >> 3;   // cluster = batch, 32 WGs
  const int b = c;
  const int tid = threadIdx.x;
  u32* slots = w.bar + c*32;
  u32 bt = 0;

  // ---- initial state: h0 real (packed), other rotation slots poisoned ----
  if (tid < 16){
    gst(&w.hbuf[HPX(0, b, wg, tid)], 0.f);
    #pragma unroll
    for (int s2 = 1; s2 < 4; s2++) gst(&w.hbuf[HPX(s2, b, wg, tid)], sentf());
    #pragma unroll
    for (int s2 = 0; s2 < 4; s2++) gst(&w.h1buf[HPX(s2, b, wg, tid)], sentf());
    #pragma unroll
    for (int s2 = 0; s2 < 3; s2++) gst(&w.h2buf[HPX(s2, b, wg, tid)], sentf());
  }
  if (tid < 128){
    #pragma unroll
    for (int s2 = 0; s2 < 3; s2++) gst(&w.partials[PPX(s2, b, wg, tid)], sentf());
  }

  // ---- encoder layer1 input GEMM (xi1 = emb @ Wi1^T + bi1), WG-private ----
  for (int i = tid; i < 16*256; i += TPB){
    int r = i >> 8, j = i & 255;
    WaE[r*264 + j] = f2b(in.enc_Wi1[((size_t)(wg*16 + r))*E_ + j]);
  }
  if (tid < 16) bscan[tid] = in.enc_bi1[wg*16 + tid];
  __syncthreads();
  for (int k0 = 0; k0 < 8; k0++){
    for (int it = 0; it < 16; it++){
      int tok = in.enc_input[b*SE_ + k0*16 + it];
      stgE[it*256 + tid] = in.enc_emb[(size_t)tok*E_ + tid];
    }
    __syncthreads();
    int r = tid & 15, tt = tid >> 4;
    float acc = 0.f;
    #pragma unroll 16
    for (int j = 0; j < 256; j += 2){
      u32 p = *(const u32*)&WaE[r*264 + j];
      float w0, w1; b2f2(p, w0, w1);
      float2 x = *(const float2*)&stgE[tt*256 + j];
      acc += w0*x.x + w1*x.y;
    }
    w.xi1[((size_t)b*SE_ + k0*16 + tt)*H_ + wg*16 + r] = acc + bscan[r];
    __syncthreads();
  }
  cbar(slots, wg, ++bt);

  // ---- encoder layer1 scan ----
  enc_scan(w, in.enc_Wh1, in.enc_bh1, w.xi1, w.out1, b, wg, WbE, xvh, bscan);
  cbar(slots, wg, ++bt);

  // ---- xi2 = out1 @ Wi2^T + bi2 ; re-poison hbuf slots 1..3 for L2 scan ----
  for (int i = tid; i < 16*512; i += TPB){
    int r = i >> 9, j = i & 511;
    WaE[r*522 + j] = f2b(in.enc_Wi2[((size_t)(wg*16 + r))*H_ + j]);
  }
  if (tid < 16){
    bscan[tid] = in.enc_bi2[wg*16 + tid];
    #pragma unroll
    for (int s2 = 1; s2 < 4; s2++) gst(&w.hbuf[HPX(s2, b, wg, tid)], sentf());
  }
  __syncthreads();
  {
    u16* stg2 = (u16*)stgE;
    for (int k0 = 0; k0 < 8; k0++){
      for (int it = 0; it < 16; it++){
        size_t base = ((size_t)b*SE_ + k0*16 + it)*H_;
        stg2[it*512 + tid]       = f2b(gld(&w.out1[base + tid]));
        stg2[it*512 + tid + 256] = f2b(gld(&w.out1[base + tid + 256]));
      }
      __syncthreads();
      int r = tid & 15, tt = tid >> 4;
      float acc = 0.f;
      #pragma unroll 16
      for (int j = 0; j < 512; j += 2){
        u32 p  = *(const u32*)&WaE[r*522 + j];
        u32 s2 = *(const u32*)&stg2[tt*512 + j];
        float w0, w1, s0, s1; b2f2(p, w0, w1); b2f2(s2, s0, s1);
        acc += w0*s0 + w1*s1;
      }
      w.xi2[((size_t)b*SE_ + k0*16 + tt)*H_ + wg*16 + r] = acc + bscan[r];
      __syncthreads();
    }
  }
  cbar(slots, wg, ++bt);

  // ---- encoder layer2 scan (initial hidden = L1 final, already in slot 0) ----
  enc_scan(w, in.enc_Wh2, in.enc_bh2, w.xi2, w.encout, b, wg, WbE, xvh, bscan);
  cbar(slots, wg, ++bt);

  // ======== decoder setup ========
  for (int i = tid; i < 16*768; i += TPB)
    WRG[i] = in.dec_Wi1[(size_t)(wg*16 + i/768)*768 + (i - (i/768)*768)];
  for (int tb = 0; tb < 32; tb++){
    __syncthreads();
    for (int i = tid; i < 8*256; i += TPB){
      int tt = tb*8 + (i >> 8);
      int tok = in.target[b*SD_ + (tt == 0 ? 0 : tt - 1)];
      STG[i] = in.dec_emb[(size_t)tok*E_ + (i & 255)];
    }
    __syncthreads();
    int r = tid >> 4, sl = tid & 15;
    for (int t2 = 0; t2 < 8; t2++){
      float acc = 0.f;
      #pragma unroll
      for (int k = 0; k < 8; k++){
        int j = 2*sl + 32*k;
        float2 wv = *(const float2*)&WRG[r*768 + j];
        float2 xx = *(const float2*)&STG[t2*256 + j];
        acc += wv.x*xx.x + wv.y*xx.y;
      }
      acc = red16(acc);
      if (sl == 0) w.xe[((size_t)b*SD_ + tb*8 + t2)*H_ + wg*16 + r] = acc;
    }
  }
  for (int sb = 0; sb < 32; sb++){
    __syncthreads();
    for (int i = tid; i < 4*512; i += TPB)
      STG[i] = gld(&w.encout[((size_t)b*SE_ + sb*4 + (i >> 9))*H_ + (i & 511)]);
    __syncthreads();
    int r = tid >> 4, sl = tid & 15;
    const float* wer = in.attn_We + (size_t)(wg*16 + r)*H_;
    float a0=0.f, a1=0.f, a2=0.f, a3=0.f;
    float p0=0.f, p1=0.f, p2=0.f, p3=0.f;
    #pragma unroll
    for (int k = 0; k < 16; k++){
      int j = 2*sl + 32*k;
      float2 wv = *(const float2*)&wer[j];
      float2 x0 = *(const float2*)&STG[j];
      float2 x1 = *(const float2*)&STG[512 + j];
      float2 x2 = *(const float2*)&STG[1024 + j];
      float2 x3 = *(const float2*)&STG[1536 + j];
      a0 += wv.x*x0.x + wv.y*x0.y;  a1 += wv.x*x1.x + wv.y*x1.y;
      a2 += wv.x*x2.x + wv.y*x2.y;  a3 += wv.x*x3.x + wv.y*x3.y;
      float2 cv = *(const float2*)&WRG[r*768 + 256 + j];
      p0 += cv.x*x0.x + cv.y*x0.y;  p1 += cv.x*x1.x + cv.y*x1.y;
      p2 += cv.x*x2.x + cv.y*x2.y;  p3 += cv.x*x3.x + cv.y*x3.y;
    }
    a0 = red16(a0); a1 = red16(a1); a2 = red16(a2); a3 = red16(a3);
    p0 = red16(p0); p1 = red16(p1); p2 = red16(p2); p3 = red16(p3);
    if (sl == 0){
      float bed = in.attn_be[wg*16 + r];
      pes[(sb*4 + 0)*17 + r] = a0 + bed;
      pes[(sb*4 + 1)*17 + r] = a1 + bed;
      pes[(sb*4 + 2)*17 + r] = a2 + bed;
      pes[(sb*4 + 3)*17 + r] = a3 + bed;
      Pm[r*128 + sb*4 + 0] = p0;  Pm[r*128 + sb*4 + 1] = p1;
      Pm[r*128 + sb*4 + 2] = p2;  Pm[r*128 + sb*4 + 3] = p3;
    }
  }
  __syncthreads();
  // (s4) decoder weight slices (f16, stride WS) + biases + h2(-1) publication
  for (int i = tid; i < 16*512; i += TPB){
    int r = i >> 9, j = i & 511;
    size_t o = ((size_t)(wg*16 + r))*H_ + j;
    Wh1s[r*WS + j] = f2h(in.dec_Wh1[o]);
    Ws2s[r*WS + j] = f2h(in.dec_Wi2[o] + in.dec_Wh2[o]);
    Wats[r*WS + j] = f2h(in.attn_Wh[o]);
  }
  if (tid < 16){
    int row = wg*16 + tid;
    b1s[tid] = in.dec_bi1[row] + in.dec_bh1[row];
    b2s[tid] = in.dec_bi2[row] + in.dec_bh2[row];
    bhs[tid] = in.attn_bh[row];
    Vs[tid]  = in.attn_V[row];
    float hv = gld(&w.hbuf[HPX(0, b, wg, tid)]);   // encoder final hidden
    gst(&w.h2buf[HPX(3, b, wg, tid)], hv);
  }
  if (tid == 0) scr[8] = in.attn_bV[0];
  cbar(slots, wg, ++bt);
  const float bVv = scr[8];

  // ---- bootstrap: partials(-1) into slot 3 ----
  {
    pollgather_h(&w.h2buf[HPB(3, b)], xv2h);
    __syncthreads();
    int r = tid >> 4, sl = tid & 15;
    float acc = 0.f;
    #pragma unroll
    for (int k = 0; k < 16; k++){
      int jj = sl + 16*k;
      acc = dot2h(*(const half2v*)&Wats[r*WS + 2*jj], xv2h[jj], acc);
    }
    acc = red16(acc);
    if (sl == 0) qs[r] = acc + bhs[r];
    __syncthreads();
    if (tid < 128){
      float part = 0.f;
      #pragma unroll
      for (int di = 0; di < 16; di++)
        part += Vs[di] * ftanh(pes[tid*17 + di] + qs[di]);
      gst(&w.partials[PPX(3, b, wg, tid)], part);
    }
  }
  cbar(slots, wg, ++bt);

  // ---- decoder main loop: R7 protocol, f16 compute, q-first ordering ----
  const int r = tid >> 4, sl = tid & 15;
  for (int t = 0; t < SD_; t++){
    const int sA = (t+3)&3;     // gen t-1 slot (h2, partials)
    const int sB = t&3;         // gen t slot (h1, h2)
    const int sP = (t+1)&3;     // slot to poison
    // ===== P13 =====
    pollgather_h(&w.h2buf[HPB(sA, b)], xv2h);
    __syncthreads();
    {   // q matvec first (shortest path to the partials rendezvous)
      float aq = 0.f;
      #pragma unroll
      for (int k = 0; k < 16; k++){
        int jj = sl + 16*k;
        aq = dot2h(*(const half2v*)&Wats[r*WS + 2*jj], xv2h[jj], aq);
      }
      aq = red16(aq);
      if (sl == 0) qs[r] = aq + bhs[r];
    }
    __syncthreads();
    // publish partials ASAP
    if (tid < 128){
      float part = 0.f;
      #pragma unroll
      for (int di = 0; di < 16; di++)
        part += Vs[di] * ftanh(pes[tid*17 + di] + qs[di]);
      gst(&w.partials[PPX(sA, b, wg, tid)], part);
    }
    // ah = Wh1.h2 computed DURING the partials flight
    float ah = 0.f;
    #pragma unroll
    for (int k = 0; k < 16; k++){
      int jj = sl + 16*k;
      ah = dot2h(*(const half2v*)&Wh1s[r*WS + 2*jj], xv2h[jj], ah);
    }
    // partials allgather + softmax (batched reload per round, R7-style)
    if (tid < 128){
      const float* pb = &w.partials[PPB(sA, b)];
      float sum;
      for (;;){
        bool ok = true; sum = bVv;
        #pragma unroll
        for (int k = 0; k < 32; k++){
          float x = gld(pb + k*128 + tid);
          ok = ok && !issent(x);
          sum += x;
        }
        if (__all(ok)) break;
        __builtin_amdgcn_s_sleep(1);
      }
      float e = __expf(sum);
      es[tid] = e;
      float d = e;
      d += __shfl_xor(d, 1);  d += __shfl_xor(d, 2);  d += __shfl_xor(d, 4);
      d += __shfl_xor(d, 8);  d += __shfl_xor(d, 16); d += __shfl_xor(d, 32);
      if ((tid & 63) == 0) scr[tid >> 6] = d;
    }
    __syncthreads();
    {
      float rden = 1.f / (scr[0] + scr[1]);
      float accP = 0.f;
      #pragma unroll
      for (int k = 0; k < 8; k++){
        int s = sl + 16*k;
        accP += Pm[r*128 + s] * es[s];
      }
      float tot = red16(ah + accP*rden);
      if (sl == 0){
        int row = wg*16 + r;
        float h1v = ftanh(tot + w.xe[((size_t)b*SD_ + t)*H_ + row] + b1s[r]);
        gst(&w.h1buf[HPX(sB, b, wg, r)], h1v);
        gst(&w.h2buf[HPX(sP, b, wg, r)], sentf());       // poison h2 slot t+1
      }
      if (tid < 128)
        gst(&w.partials[PPX(sP, b, wg, tid)], sentf());  // poison partials t+1
    }
    // ===== P2 =====
    pollgather_h(&w.h1buf[HPB(sB, b)], xvh);
    __syncthreads();
    {
      float acc = 0.f;
      #pragma unroll
      for (int k = 0; k < 16; k++){
        int jj = sl + 16*k;
        acc = dot2h(*(const half2v*)&Ws2s[r*WS + 2*jj], xvh[jj], acc);
      }
      acc = red16(acc);
      if (sl == 0){
        float h2v = ftanh(acc + b2s[r]);
        int row = wg*16 + r;
        gst(&w.h2buf[HPX(sB, b, wg, r)], h2v);
        w.h2all[((size_t)(b*SD_ + t))*H_ + row] = f2b(h2v);   // cross-kernel only
        gst(&w.h1buf[HPX((t+2)&3, b, wg, r)], sentf());       // poison h1 slot t+2
      }
    }
    asm volatile("s_waitcnt vmcnt(0)" ::: "memory");   // poisons before next-step stores
    __syncthreads();
  }
}

// ---------------- out_W fp32 -> bf16 ----------------
__global__ void cvt_bf16(const float* __restrict__ src, u16* __restrict__ dst, int n4){
  int idx = blockIdx.x*blockDim.x + threadIdx.x;
  int stride = gridDim.x*blockDim.x;
  for (int i = idx; i < n4; i += stride){
    float4 v = ((const float4*)src)[i];
    ushort4 o;
    o.x = f2b(v.x); o.y = f2b(v.y); o.z = f2b(v.z); o.w = f2b(v.w);
    ((ushort4*)dst)[i] = o;
  }
}

// ---------------- output projection GEMM: [2048,512] x [32000,512]^T + bias ----------------
__global__ __launch_bounds__(256, 1) void out_gemm(const u16* __restrict__ A,
    const u16* __restrict__ Bw, const float* __restrict__ bias, float* __restrict__ out)
{
  __shared__ u16 Al[128*32];
  __shared__ u16 Bl[128*32];
  int tid = threadIdx.x;
  int bidm = blockIdx.x & 15, bidn = blockIdx.x >> 4;
  int m0 = bidm*128, n0 = bidn*128;
  int wv = tid >> 6, l = tid & 63;
  int wm = wv >> 1, wn = wv & 1;
  f32x4 acc[4][4] = {};
  for (int k0 = 0; k0 < 512; k0 += 32){
    __syncthreads();
    #pragma unroll
    for (int rd = 0; rd < 2; rd++){
      int ci = rd*256 + wv*64 + l;
      int row = ci >> 2, qq = ci & 3;
      const u16* ga = A  + (size_t)(m0 + row)*512 + k0 + qq*8;
      const u16* gb = Bw + (size_t)(n0 + row)*512 + k0 + qq*8;
      __builtin_amdgcn_global_load_lds((const __attribute__((address_space(1))) unsigned int*)ga,
          (__attribute__((address_space(3))) unsigned int*)(Al + (rd*256 + wv*64)*8), 16, 0, 0);
      __builtin_amdgcn_global_load_lds((const __attribute__((address_space(1))) unsigned int*)gb,
          (__attribute__((address_space(3))) unsigned int*)(Bl + (rd*256 + wv*64)*8), 16, 0, 0);
    }
    __syncthreads();
    short8 af[4], bf[4];
    int lr = l & 15, lk = l >> 4;
    #pragma unroll
    for (int mi = 0; mi < 4; mi++)
      af[mi] = *(const short8*)(Al + (size_t)(wm*64 + mi*16 + lr)*32 + lk*8);
    #pragma unroll
    for (int ni = 0; ni < 4; ni++)
      bf[ni] = *(const short8*)(Bl + (size_t)(wn*64 + ni*16 + lr)*32 + lk*8);
    #pragma unroll
    for (int mi = 0; mi < 4; mi++)
      #pragma unroll
      for (int ni = 0; ni < 4; ni++)
        acc[mi][ni] = __builtin_amdgcn_mfma_f32_16x16x32_bf16(af[mi], bf[ni], acc[mi][ni], 0, 0, 0);
  }
  #pragma unroll
  for (int ni = 0; ni < 4; ni++){
    int col = n0 + wn*64 + ni*16 + (l & 15);
    float bb = bias[col];
    #pragma unroll
    for (int mi = 0; mi < 4; mi++){
      int row = m0 + wm*64 + mi*16 + (l >> 4)*4;
      #pragma unroll
      for (int r = 0; r < 4; r++)
        out[(size_t)(row + r)*32000 + col] = acc[mi][ni][r] + bb;
    }
  }
}

// ---------------- host ----------------
extern "C" void kernel_launch(void* const* d_in, const int* in_sizes, int n_in,
                              void* d_out, int out_size, void* d_ws, size_t ws_size,
                              hipStream_t stream)
{
  (void)in_sizes; (void)n_in; (void)out_size; (void)ws_size;
  Inputs in;
  in.enc_input = (const int*)d_in[0];
  in.target    = (const int*)d_in[1];
  in.enc_emb   = (const float*)d_in[2];
  in.enc_Wi1   = (const float*)d_in[3];  in.enc_bi1 = (const float*)d_in[4];
  in.enc_Wh1   = (const float*)d_in[5];  in.enc_bh1 = (const float*)d_in[6];
  in.enc_Wi2   = (const float*)d_in[7];  in.enc_bi2 = (const float*)d_in[8];
  in.enc_Wh2   = (const float*)d_in[9];  in.enc_bh2 = (const float*)d_in[10];
  in.dec_emb   = (const float*)d_in[11];
  in.attn_We   = (const float*)d_in[12]; in.attn_be = (const float*)d_in[13];
  in.attn_Wh   = (const float*)d_in[14]; in.attn_bh = (const float*)d_in[15];
  in.attn_V    = (const float*)d_in[16]; in.attn_bV = (const float*)d_in[17];
  in.dec_Wi1   = (const float*)d_in[18]; in.dec_bi1 = (const float*)d_in[19];
  in.dec_Wh1   = (const float*)d_in[20]; in.dec_bh1 = (const float*)d_in[21];
  in.dec_Wi2   = (const float*)d_in[22]; in.dec_bi2 = (const float*)d_in[23];
  in.dec_Wh2   = (const float*)d_in[24]; in.dec_bh2 = (const float*)d_in[25];
  in.out_W     = (const float*)d_in[26]; in.out_b   = (const float*)d_in[27];

  char* ws = (char*)d_ws;
  char* od = (char*)d_out;
  Wksp w;
  w.bar      = (u32*)ws;                      // 1 KB (memset each call)
  w.hbuf     = (float*)(ws + 1024);           // packed [4][8][32][16]
  w.h1buf    = (float*)(ws + 66560);          // packed [4][8][32][16]
  w.h2buf    = (float*)(ws + 132096);         // packed [4][8][32][16]
  w.partials = (float*)(ws + 197632);         // packed [4][8][32][128]
  w.h2all    = (u16*)  (ws + 721920);         // [2048][512] bf16
  w.wb       = (u16*)  (ws + 2819072);        // [32000][512] bf16
  w.xi1    = (float*)(od);
  w.xi2    = (float*)(od + (1 << 21));
  w.out1   = (float*)(od + 2*(1 << 21));
  w.encout = (float*)(od + 3*(1 << 21));
  w.xe     = (float*)(od + 4*(1 << 21));      // [8][256][512] f32

  hipMemsetAsync(d_ws, 0, 1024, stream);
  cvt_bf16<<<dim3(4096), dim3(256), 0, stream>>>(in.out_W, w.wb, 32000*512/4);
  seq2seq_persist<<<dim3(256), dim3(TPB), 0, stream>>>(in, w);
  out_gemm<<<dim3(4000), dim3(256), 0, stream>>>(w.h2all, w.wb, in.out_b, (float*)d_out);
}